// Round 10
// baseline (2153.944 us; speedup 1.0000x reference)
//
#include <hip/hip_runtime.h>
#include <cstdint>
#include <cstddef>

// ---------------------------------------------------------------------------
// Trainer_91216515433187: BN + Dense + LSTM encoder (1024 steps) + 35-step
// autoregressive LSTM decoder.
//
// Round 11: R10 (tagged flag-free exchange) with the import latency taken off
// the critical path:
//   * the per-lane tagged dwordx4 import is issued FIRST after the step
//     barrier; phase-A (acc init + x-affine + own-half MFMAs, ~450cy) runs
//     while it is in flight; vmcnt(0)+tag-check+retry+LDS-stage after.
//   * pulse prefetch moved AFTER the import check so the import vmcnt(0)
//     never waits on an HBM px load (px has a full step of slack).
// Everything else identical to R10: 32 WGs = 16 tiles x 2 halves; weights
// AGPR-pinned register-resident; exchange atoms u32 {tag=step, f16}; export
// = fire-and-forget sc0sc1 stores inside gates; raw lgkm-only barriers (2
// per step); import staged to an LDS mirror cooperatively (1 load/lane).
// ---------------------------------------------------------------------------

typedef _Float16 h8 __attribute__((ext_vector_type(8)));
typedef float f4 __attribute__((ext_vector_type(4)));
typedef uint32_t ui4 __attribute__((ext_vector_type(4)));

// ws byte offsets
#define WS_HBUF   0         // tagged h: 2 par x 16 tiles x 2 halves x 8192 B = 524288
#define WS_RKT    524288    // 1024 cols x 256 k f16 = 524288
#define WS_WEFF   1048576   // 1024 cols x 8 f f16 = 16384
#define WS_WMLP   1064960   // 2 e x 256 k f16 = 1024
#define WS_DEFF   1065984   // f32 [2][1024] = 8192
#define WS_ZB     1074176   // 1024 f32
#define WS_DB     1078272   // 1024 f32 -> end 1082368

// LDS layout (24 KB)
#define LB_HO  0            // own h: 2 par x 4096
#define LB_HP  8192         // partner h mirror: 2 par x 4096
#define LZB    16384        // zbias [g4][cloc128] f32 = 2048
#define LDB    18432        // dbias
#define LD0    20480        // Deff0
#define LD1    22528        // Deff1
#define LDS_SZ 24576

__device__ __forceinline__ float fexp2(float x){
#if __has_builtin(__builtin_amdgcn_exp2f)
  return __builtin_amdgcn_exp2f(x);
#else
  return exp2f(x);
#endif
}
__device__ __forceinline__ float frcp(float x){
#if __has_builtin(__builtin_amdgcn_rcpf)
  return __builtin_amdgcn_rcpf(x);
#else
  return 1.f / x;
#endif
}
__device__ __forceinline__ float sigf(float x){
  return frcp(1.f + fexp2(-1.44269504f * x));
}
__device__ __forceinline__ float tanh_f(float x){
  return 2.f * frcp(1.f + fexp2(-2.88539008f * x)) - 1.f;
}
__device__ __forceinline__ uint32_t f16bits(_Float16 h){
  union { _Float16 h; uint16_t u; } t; t.h = h; return (uint32_t)t.u;
}

// IF-coherent (cache-bypassing) ops
__device__ __forceinline__ ui4 ld_b128_sys(uint64_t addr){
  ui4 r;
  asm volatile("global_load_dwordx4 %0, %1, off sc0 sc1"
               : "=v"(r) : "v"(addr) : "memory");
  return r;
}
__device__ __forceinline__ void st_b32_sys(uint64_t addr, uint32_t v){
  asm volatile("global_store_dword %0, %1, off sc0 sc1"
               :: "v"(addr), "v"(v) : "memory");
}

// raw barrier: LDS drain only — global stores/loads stay in flight
#define BAR()                                                                  \
  do {                                                                         \
    asm volatile("s_waitcnt lgkmcnt(0)" ::: "memory");                         \
    __builtin_amdgcn_s_barrier();                                              \
    asm volatile("" ::: "memory");                                             \
  } while (0)

__global__ void zero_ws_k(uint32_t* __restrict__ p, int nw){
  int i = blockIdx.x * 256 + threadIdx.x;
  if (i < nw) p[i] = 0u;
}

// grid 1024 x 256 threads (known-correct)
__global__ void precompute_k(const float* __restrict__ bn_gamma,
                             const float* __restrict__ bn_beta,
                             const float* __restrict__ bn_mean,
                             const float* __restrict__ bn_var,
                             const float* __restrict__ W_pulse,   // (8,256)
                             const float* __restrict__ b_pulse,   // (256)
                             const float* __restrict__ lstm_k,    // (256,1024)
                             const float* __restrict__ lstm_rk,   // (256,1024)
                             const float* __restrict__ lstm_b,    // (1024)
                             const float* __restrict__ W_eis,     // (2,256)
                             const float* __restrict__ b_eis,     // (256)
                             const float* __restrict__ W_mlp,     // (256,2)
                             _Float16* __restrict__ rkT,          // [col][k]
                             _Float16* __restrict__ WeffT,        // [col][f]
                             _Float16* __restrict__ WmlpT,        // [e][k]
                             float* __restrict__ Deff,            // [e][col]
                             float* __restrict__ zbias,
                             float* __restrict__ dbias)
{
  int gid = blockIdx.x * 256 + threadIdx.x;   // 0..262143
  {
    int col = gid >> 8;
    int k   = gid & 255;
    rkT[col * 256 + k] = (_Float16)lstm_rk[k * 1024 + col];
  }
  if (gid < 512) {
    int e = gid >> 8, k = gid & 255;
    WmlpT[e * 256 + k] = (_Float16)W_mlp[k * 2 + e];
  }
  if (gid < 1024) {
    int j = gid;
    float a[8], bv[8];
#pragma unroll
    for (int f = 0; f < 8; ++f) {
      float af = bn_gamma[f] * rsqrtf(bn_var[f] + 1e-3f);
      a[f]  = af;
      bv[f] = bn_beta[f] - bn_mean[f] * af;
    }
    float m[8] = {0,0,0,0,0,0,0,0};
    float d0 = 0.f, d1 = 0.f, zb2 = 0.f, db2 = 0.f;
    for (int k = 0; k < 256; ++k) {
      float lk = lstm_k[k * 1024 + j];
#pragma unroll
      for (int f = 0; f < 8; ++f) m[f] += W_pulse[f * 256 + k] * lk;
      d0  += W_eis[k]       * lk;
      d1  += W_eis[256 + k] * lk;
      zb2 += b_pulse[k] * lk;
      db2 += b_eis[k]   * lk;
    }
    float zb = lstm_b[j] + zb2;
#pragma unroll
    for (int f = 0; f < 8; ++f) {
      zb += bv[f] * m[f];
      WeffT[j * 8 + f] = (_Float16)(a[f] * m[f]);
    }
    zbias[j] = zb;
    dbias[j] = lstm_b[j] + db2;
    Deff[j]        = d0;
    Deff[1024 + j] = d1;
  }
}

// early issue: this wave's 1KB tagged slice of the partner half
#define IMPORT_ISSUE(p_)                                                       \
  iv = ld_b128_sys(gpa + (uint64_t)((uint32_t)(p_) * 262144u + ioff));

// finish: wait, tag-check (retry reissues), extract, stage LDS mirror
#define IMPORT_FINISH(p_, Texp_)                                               \
  {                                                                            \
    const uint64_t ib = gpa + (uint64_t)((uint32_t)(p_) * 262144u + ioff);     \
    const uint32_t te = (uint32_t)(Texp_);                                     \
    while (true) {                                                             \
      asm volatile("s_waitcnt vmcnt(0)" ::: "memory");                         \
      __builtin_amdgcn_sched_barrier(0);                                       \
      bool ok = ((iv[0] >> 16) == te) && ((iv[1] >> 16) == te) &&              \
                ((iv[2] >> 16) == te) && ((iv[3] >> 16) == te);                \
      if (__all(ok)) break;                                                    \
      iv = ld_b128_sys(ib);                                                    \
    }                                                                          \
    uint32_t pk0 = __builtin_amdgcn_perm(iv[1], iv[0], 0x05040100u);           \
    uint32_t pk1 = __builtin_amdgcn_perm(iv[3], iv[2], 0x05040100u);           \
    const uint32_t lo_ = (uint32_t)(LB_HP + (p_) * 4096) + (ioff >> 1);        \
    *reinterpret_cast<uint32_t*>(&smem[lo_])     = pk0;                        \
    *reinterpret_cast<uint32_t*>(&smem[lo_ + 4]) = pk1;                        \
  }

#define LOAD_HAO(p_)                                                           \
  h8 haO[4];                                                                   \
  _Pragma("unroll") for (int i_ = 0; i_ < 4; ++i_)                             \
    haO[i_] = *reinterpret_cast<const h8*>(                                    \
        &smem[LB_HO + (p_) * 4096 + lrd + (uint32_t)(i_ * 1024)]);

#define LOAD_HAP(p_)                                                           \
  h8 haP[4];                                                                   \
  _Pragma("unroll") for (int i_ = 0; i_ < 4; ++i_)                             \
    haP[i_] = *reinterpret_cast<const h8*>(                                    \
        &smem[LB_HP + (p_) * 4096 + lrd + (uint32_t)(i_ * 1024)]);

#define MM_OWN()                                                               \
  _Pragma("unroll") for (int i_ = 0; i_ < 4; ++i_)                             \
  _Pragma("unroll") for (int g_ = 0; g_ < 4; ++g_)                             \
    acc[g_] = __builtin_amdgcn_mfma_f32_16x16x32_f16(haO[i_], WO[i_][g_],      \
                                                     acc[g_], 0, 0, 0);

#define MM_PAR()                                                               \
  _Pragma("unroll") for (int i_ = 0; i_ < 4; ++i_)                             \
  _Pragma("unroll") for (int g_ = 0; g_ < 4; ++g_)                             \
    acc[g_] = __builtin_amdgcn_mfma_f32_16x16x32_f16(haP[i_], WP[i_][g_],      \
                                                     acc[g_], 0, 0, 0);

// gates -> own-h LDS (parity pw) + fire-and-forget tagged global stores,
// each issued as soon as its hv is ready
#define GATES_STORES(pw_, Twr_)                                                \
  {                                                                            \
    const uint64_t gw = gme + (uint64_t)((uint32_t)(pw_) * 262144u + 2u * lwr);\
    const uint32_t thi = ((uint32_t)(Twr_)) << 16;                             \
    _Pragma("unroll") for (int r_ = 0; r_ < 4; ++r_) {                         \
      float iv_ = sigf(acc[0][r_]);                                            \
      float fv_ = sigf(acc[1][r_]);                                            \
      float gv_ = tanh_f(acc[2][r_]);                                          \
      float ov_ = sigf(acc[3][r_]);                                            \
      float cc_ = fv_ * cf[r_] + iv_ * gv_;                                    \
      cf[r_] = cc_;                                                            \
      _Float16 hv_ = (_Float16)(ov_ * tanh_f(cc_));                            \
      st_b32_sys(gw + (uint64_t)(r_ * 32), thi | f16bits(hv_));                \
      *reinterpret_cast<_Float16*>(                                            \
          &smem[LB_HO + (pw_) * 4096 + lwr + (uint32_t)(r_ * 16)]) = hv_;      \
    }                                                                          \
  }

// 32 blocks x 512 threads: block = (tile = bid&15, half = bid>>4)
__global__ __launch_bounds__(512, 2)
void lstm_main_k(const float* __restrict__ pulse,      // (256,1024,8)
                 const float* __restrict__ embed,      // (1,2)
                 const float* __restrict__ b_mlp,      // (2)
                 const float* __restrict__ scale_w,    // (2)
                 const float* __restrict__ scale_b,    // (2)
                 const _Float16* __restrict__ rkT,
                 const _Float16* __restrict__ WeffT,
                 const _Float16* __restrict__ WmlpT,
                 const float* __restrict__ Deff,
                 const float* __restrict__ zbias,
                 const float* __restrict__ dbias,
                 char* __restrict__ hbuf,              // tagged exchange
                 float* __restrict__ out)              // (256,35,2)
{
  __shared__ alignas(16) char smem[LDS_SZ];

  const int tid  = threadIdx.x;
  const int w    = tid >> 6;
  const int lane = tid & 63;
  const int n    = lane & 15;
  const int quad = lane >> 4;
  const int bid  = blockIdx.x;
  const int tile = bid & 15;
  const int half = bid >> 4;
  const int b0   = tile * 16;
  const int cloc = w * 16 + n;                // local hidden col 0..127
  const int hcol = half * 128 + cloc;         // global hidden col

  // zero own + partner h LDS (16 KB)
  {
    f4 zz; zz[0] = zz[1] = zz[2] = zz[3] = 0.f;
    *reinterpret_cast<f4*>(&smem[tid * 16]) = zz;
    *reinterpret_cast<f4*>(&smem[8192 + tid * 16]) = zz;
  }
  // biases/Deff -> LDS (quad0 lanes cover all cloc)
  if (quad == 0) {
#pragma unroll
    for (int g = 0; g < 4; ++g) {
      int zc = g * 256 + hcol;
      *reinterpret_cast<float*>(&smem[LZB + g * 512 + cloc * 4]) = zbias[zc];
      *reinterpret_cast<float*>(&smem[LDB + g * 512 + cloc * 4]) = dbias[zc];
      *reinterpret_cast<float*>(&smem[LD0 + g * 512 + cloc * 4]) = Deff[zc];
      *reinterpret_cast<float*>(&smem[LD1 + g * 512 + cloc * 4]) = Deff[1024 + zc];
    }
  }

  h8 z8;
#pragma unroll
  for (int j = 0; j < 8; ++j) z8[j] = (_Float16)0.f;

  // ---- recurrent weights: register-resident, AGPR-pinned (R7-R10 proven) ----
  const char* rkTb = reinterpret_cast<const char*>(rkT);
  const uint32_t gbo = (uint32_t)(hcol * 512 + quad * 16);
  const uint32_t sbO = (uint32_t)(half * 256);   // own slot byte base
  const uint32_t sbP = 256u - sbO;               // partner slot byte base
  h8 WO[4][4], WP[4][4];
#pragma unroll
  for (int i = 0; i < 4; ++i)
#pragma unroll
    for (int g = 0; g < 4; ++g) {
      WO[i][g] = *reinterpret_cast<const h8*>(
          rkTb + gbo + (uint32_t)(g * 131072) + sbO + (uint32_t)(i * 64));
      asm("" : "+a"(WO[i][g]));
      WP[i][g] = *reinterpret_cast<const h8*>(
          rkTb + gbo + (uint32_t)(g * 131072) + sbP + (uint32_t)(i * 64));
      asm("" : "+a"(WP[i][g]));
    }
  h8 Wf[4];
#pragma unroll
  for (int g = 0; g < 4; ++g) {
    Wf[g] = (quad == 0)
        ? *reinterpret_cast<const h8*>(WeffT + (size_t)(g * 256 + hcol) * 8)
        : z8;
    asm("" : "+a"(Wf[g]));
  }

  // per-lane addresses
  const uint32_t lrd  = (uint32_t)(quad * 256 + n * 16);   // A-frag read
  const uint32_t lwr  = (uint32_t)((cloc >> 3) * 256 + quad * 64 + (cloc & 7) * 2);
  const uint32_t ioff = (uint32_t)(w * 1024 + lane * 16);  // tagged import slice
  const uint64_t hb   = (uint64_t)(uintptr_t)hbuf;
  const uint64_t gme  = hb + (uint64_t)((tile * 2 + half) * 8192);
  const uint64_t gpa  = hb + (uint64_t)((tile * 2 + (1 - half)) * 8192);

  f4 cf; cf[0] = cf[1] = cf[2] = cf[3] = 0.f;
  const float* prow = pulse + (size_t)(b0 + n) * 8192;    // quad0 lanes

  // prologue: x(0) prefetch
  f4 px0, px1;
  px0[0]=px0[1]=px0[2]=px0[3]=0.f; px1[0]=px1[1]=px1[2]=px1[3]=0.f;
  if (quad == 0) {
    const f4* pp = reinterpret_cast<const f4*>(prow);
    px0 = pp[0]; px1 = pp[1];
  }

  __syncthreads();

  // ---------------- encoder: t = 0..1023 ----------------
#pragma unroll 1
  for (int t = 0; t < 1024; ++t) {
    const int p = t & 1, pw = p ^ 1;

    ui4 iv;
    IMPORT_ISSUE(p);                     // first thing: load flies under phase-A

    // phase A (all waves): acc init + x-affine + own-half MFMAs
    f4 acc[4];
#pragma unroll
    for (int g = 0; g < 4; ++g) {
      float zv = *reinterpret_cast<const float*>(
          &smem[LZB + (uint32_t)(g * 512 + cloc * 4)]);
      acc[g][0] = zv; acc[g][1] = zv; acc[g][2] = zv; acc[g][3] = zv;
    }
    h8 pa = z8;
    if (quad == 0) {
      pa[0] = (_Float16)px0[0]; pa[1] = (_Float16)px0[1];
      pa[2] = (_Float16)px0[2]; pa[3] = (_Float16)px0[3];
      pa[4] = (_Float16)px1[0]; pa[5] = (_Float16)px1[1];
      pa[6] = (_Float16)px1[2]; pa[7] = (_Float16)px1[3];
    }
#pragma unroll
    for (int g = 0; g < 4; ++g)
      acc[g] = __builtin_amdgcn_mfma_f32_16x16x32_f16(pa, Wf[g], acc[g], 0, 0, 0);

    LOAD_HAO(p);
    MM_OWN();

    IMPORT_FINISH(p, t);                 // wait (overlapped) + stage mirror

    // x(t+1) prefetch AFTER the import vmcnt — off the exchange path
    if (quad == 0) {
      int tp = (t + 1 < 1024) ? t + 1 : 1023;
      const f4* pp = reinterpret_cast<const f4*>(prow) + tp * 2;
      px0 = pp[0]; px1 = pp[1];
    }

    BAR();                               // partner h(t) staged in mirror

    LOAD_HAP(p);
    MM_PAR();

    GATES_STORES(pw, t + 1);             // LDS own h(t+1) + tagged export
    BAR();
  }

  // ---------------- decoder: 35 steps ----------------
  const float swv = (n < 2) ? scale_w[n] : 0.f;
  const float sbv = (n < 2) ? scale_b[n] : 0.f;
  const float bmv = (n < 2) ? b_mlp[n]   : 0.f;
  const char* wmlpb = reinterpret_cast<const char*>(WmlpT);
  float tk0[4], tk1[4];
  {
    float e0 = embed[0], e1 = embed[1];
#pragma unroll
    for (int r = 0; r < 4; ++r) { tk0[r] = e0; tk1[r] = e1; }
  }

#pragma unroll 1
  for (int s = 0; s < 35; ++s) {
    const int T = 1024 + s;
    const int p = T & 1, pw = p ^ 1;

    ui4 iv;
    IMPORT_ISSUE(p);
    IMPORT_FINISH(p, T);
    BAR();                               // h(T) complete in LDS

    LOAD_HAO(p);
    LOAD_HAP(p);

    if (s > 0) {
      // pred_{s-1} = h(T) @ W_mlp + b_mlp (all waves)
      f4 pf; pf[0] = bmv; pf[1] = bmv; pf[2] = bmv; pf[3] = bmv;
#pragma unroll
      for (int i = 0; i < 4; ++i) {
        h8 wb = (n < 2)
            ? *reinterpret_cast<const h8*>(
                  wmlpb + (uint32_t)(n * 512 + quad * 16) + sbO + (uint32_t)(i * 64))
            : z8;
        pf = __builtin_amdgcn_mfma_f32_16x16x32_f16(haO[i], wb, pf, 0, 0, 0);
      }
#pragma unroll
      for (int i = 0; i < 4; ++i) {
        h8 wb = (n < 2)
            ? *reinterpret_cast<const h8*>(
                  wmlpb + (uint32_t)(n * 512 + quad * 16) + sbP + (uint32_t)(i * 64))
            : z8;
        pf = __builtin_amdgcn_mfma_f32_16x16x32_f16(haP[i], wb, pf, 0, 0, 0);
      }
      if (half == 0 && w == 0 && n < 2) {
#pragma unroll
        for (int r = 0; r < 4; ++r)
          out[((size_t)(b0 + quad * 4 + r) * 35 + (s - 1)) * 2 + n] =
              pf[r] * swv + sbv;
      }
#pragma unroll
      for (int r = 0; r < 4; ++r) {
        tk0[r] = __shfl(pf[r], quad * 16);
        tk1[r] = __shfl(pf[r], quad * 16 + 1);
      }
    }

    f4 acc[4];
#pragma unroll
    for (int g = 0; g < 4; ++g) {
      float dbv = *reinterpret_cast<const float*>(
          &smem[LDB + (uint32_t)(g * 512 + cloc * 4)]);
      float d0v = *reinterpret_cast<const float*>(
          &smem[LD0 + (uint32_t)(g * 512 + cloc * 4)]);
      float d1v = *reinterpret_cast<const float*>(
          &smem[LD1 + (uint32_t)(g * 512 + cloc * 4)]);
#pragma unroll
      for (int r = 0; r < 4; ++r)
        acc[g][r] = dbv + tk0[r] * d0v + tk1[r] * d1v;
    }
    MM_OWN();
    MM_PAR();

    GATES_STORES(pw, T + 1);
    BAR();
  }

  // epilogue: import h(1059) (parity 1, tag 1059), then pred_34 (half0 out)
  {
    ui4 iv;
    IMPORT_ISSUE(1);
    IMPORT_FINISH(1, 1059);
    BAR();

    if (half == 0) {
      LOAD_HAO(1);
      LOAD_HAP(1);
      f4 pf; pf[0] = bmv; pf[1] = bmv; pf[2] = bmv; pf[3] = bmv;
#pragma unroll
      for (int i = 0; i < 4; ++i) {
        h8 wb = (n < 2)
            ? *reinterpret_cast<const h8*>(
                  wmlpb + (uint32_t)(n * 512 + quad * 16) + sbO + (uint32_t)(i * 64))
            : z8;
        pf = __builtin_amdgcn_mfma_f32_16x16x32_f16(haO[i], wb, pf, 0, 0, 0);
      }
#pragma unroll
      for (int i = 0; i < 4; ++i) {
        h8 wb = (n < 2)
            ? *reinterpret_cast<const h8*>(
                  wmlpb + (uint32_t)(n * 512 + quad * 16) + sbP + (uint32_t)(i * 64))
            : z8;
        pf = __builtin_amdgcn_mfma_f32_16x16x32_f16(haP[i], wb, pf, 0, 0, 0);
      }
      if (w == 0 && n < 2) {
#pragma unroll
        for (int r = 0; r < 4; ++r)
          out[((size_t)(b0 + quad * 4 + r) * 35 + 34) * 2 + n] = pf[r] * swv + sbv;
      }
    }
  }
}

extern "C" void kernel_launch(void* const* d_in, const int* in_sizes, int n_in,
                              void* d_out, int out_size, void* d_ws, size_t ws_size,
                              hipStream_t stream) {
  const float* pulse    = (const float*)d_in[0];
  const float* bn_gamma = (const float*)d_in[1];
  const float* bn_beta  = (const float*)d_in[2];
  const float* bn_mean  = (const float*)d_in[3];
  const float* bn_var   = (const float*)d_in[4];
  const float* W_pulse  = (const float*)d_in[5];
  const float* b_pulse  = (const float*)d_in[6];
  const float* lstm_k   = (const float*)d_in[7];
  const float* lstm_rk  = (const float*)d_in[8];
  const float* lstm_b   = (const float*)d_in[9];
  const float* embed    = (const float*)d_in[10];
  const float* W_eis    = (const float*)d_in[11];
  const float* b_eis    = (const float*)d_in[12];
  const float* W_mlp    = (const float*)d_in[13];
  const float* b_mlp    = (const float*)d_in[14];
  const float* scale_w  = (const float*)d_in[15];
  const float* scale_b  = (const float*)d_in[16];

  char* ws = (char*)d_ws;
  char*     hbuf   = ws + WS_HBUF;
  _Float16* rkT    = (_Float16*)(ws + WS_RKT);
  _Float16* WeffT  = (_Float16*)(ws + WS_WEFF);
  _Float16* WmlpT  = (_Float16*)(ws + WS_WMLP);
  float*    Deff   = (float*)(ws + WS_DEFF);
  float*    zbias  = (float*)(ws + WS_ZB);
  float*    dbias  = (float*)(ws + WS_DB);

  // zero tagged h exchange buffer: 524288/4 = 131072 words (tag 0 = step-0 valid)
  zero_ws_k<<<512, 256, 0, stream>>>((uint32_t*)d_ws, 131072);
  precompute_k<<<1024, 256, 0, stream>>>(bn_gamma, bn_beta, bn_mean, bn_var,
                                         W_pulse, b_pulse, lstm_k, lstm_rk, lstm_b,
                                         W_eis, b_eis, W_mlp,
                                         rkT, WeffT, WmlpT, Deff, zbias, dbias);
  lstm_main_k<<<32, 512, 0, stream>>>(pulse, embed, b_mlp, scale_w, scale_b,
                                      rkT, WeffT, WmlpT, Deff, zbias, dbias,
                                      hbuf, (float*)d_out);
}